// Round 1
// baseline (940.971 us; speedup 1.0000x reference)
//
#include <hip/hip_runtime.h>
#include <hip/hip_bf16.h>

// ---------------------------------------------------------------------------
// Generic tiled fp32 GEMM: C = act(A @ B + bias)
//   A: N x K (row-major, leading dim lda)
//   B: K x M (row-major, leading dim ldb), M assumed multiple of BN
//   C: N x M (leading dim ldc)
// ACT: 0 = none, 1 = relu, 2 = tanh
// ---------------------------------------------------------------------------
template<int BM, int BN, int BK, int TM, int TN, int ACT>
__global__ __launch_bounds__((BM / TM) * (BN / TN))
void gemm_k(const float* __restrict__ A, int lda,
            const float* __restrict__ B, int ldb,
            const float* __restrict__ bias,
            float* __restrict__ C, int ldc,
            int N, int K) {
    constexpr int THREADS = (BM / TM) * (BN / TN);
    __shared__ float As[BK][BM];       // transposed store: As[k][m]
    __shared__ float Bs[BK][BN + 4];   // +4 pad to break store conflicts

    const int tid  = threadIdx.x;
    const int brow = blockIdx.y * BM;
    const int bcol = blockIdx.x * BN;
    constexpr int TCOLS = BN / TN;
    const int tcol = tid % TCOLS;
    const int trow = tid / TCOLS;

    float acc[TM][TN] = {};

    for (int k0 = 0; k0 < K; k0 += BK) {
        // stage A tile (BM x BK), guarded on rows
        #pragma unroll
        for (int i = tid; i < BM * BK; i += THREADS) {
            int r = i / BK, c = i % BK;
            int gr = brow + r;
            As[c][r] = (gr < N) ? A[(size_t)gr * lda + (k0 + c)] : 0.f;
        }
        // stage B tile (BK x BN); K and M are multiples of BK/BN
        #pragma unroll
        for (int i = tid; i < BK * BN; i += THREADS) {
            int r = i / BN, c = i % BN;
            Bs[r][c] = B[(size_t)(k0 + r) * ldb + (bcol + c)];
        }
        __syncthreads();

        #pragma unroll
        for (int kk = 0; kk < BK; kk++) {
            float a[TM], b[TN];
            #pragma unroll
            for (int m = 0; m < TM; m++) a[m] = As[kk][trow * TM + m];
            #pragma unroll
            for (int n = 0; n < TN; n++) b[n] = Bs[kk][tcol * TN + n];
            #pragma unroll
            for (int m = 0; m < TM; m++)
                #pragma unroll
                for (int n = 0; n < TN; n++)
                    acc[m][n] = fmaf(a[m], b[n], acc[m][n]);
        }
        __syncthreads();
    }

    #pragma unroll
    for (int m = 0; m < TM; m++) {
        int gr = brow + trow * TM + m;
        if (gr >= N) continue;
        #pragma unroll
        for (int n = 0; n < TN; n++) {
            int gc = bcol + tcol * TN + n;
            float v = acc[m][n] + bias[gc];
            if (ACT == 1) v = fmaxf(v, 0.f);
            else if (ACT == 2) v = tanhf(v);
            C[(size_t)gr * ldc + gc] = v;
        }
    }
}

// ---------------------------------------------------------------------------
// CSR-by-destination build
// ---------------------------------------------------------------------------
__global__ void hist_k(const int* __restrict__ dst, int E, int* __restrict__ counts) {
    int i = blockIdx.x * blockDim.x + threadIdx.x;
    if (i < E) atomicAdd(&counts[dst[i]], 1);
}

// single-block scan: counts (n) -> exclusive offsets (n+1) and cursor copy
__global__ void scan_k(const int* __restrict__ counts, int* __restrict__ offsets,
                       int* __restrict__ cursor, int n, int total) {
    __shared__ int sh[1024];
    const int t = threadIdx.x;
    const int chunk = (n + 1023) >> 10;
    const int lo = t * chunk;
    const int hi = min(lo + chunk, n);
    int s = 0;
    for (int i = lo; i < hi; i++) s += counts[i];
    sh[t] = s;
    __syncthreads();
    #pragma unroll
    for (int d = 1; d < 1024; d <<= 1) {
        int v = (t >= d) ? sh[t - d] : 0;
        __syncthreads();
        sh[t] += v;
        __syncthreads();
    }
    int off = sh[t] - s;  // exclusive prefix for this thread's chunk
    for (int i = lo; i < hi; i++) {
        offsets[i] = off;
        cursor[i]  = off;
        off += counts[i];
    }
    if (t == 0) offsets[n] = total;
}

__global__ void fill_k(const int* __restrict__ src, const int* __restrict__ dst, int E,
                       int* __restrict__ cursor, int* __restrict__ sorted_src) {
    int i = blockIdx.x * blockDim.x + threadIdx.x;
    if (i < E) {
        int d = dst[i];
        int pos = atomicAdd(&cursor[d], 1);
        sorted_src[pos] = src[i];
    }
}

// ---------------------------------------------------------------------------
// Aggregate: out[node][0:256] = sum over incoming edges of t[src][0:256]
// One wave (64 lanes) per node, float4 per lane (64*16B = 1KB coalesced row).
// out has row stride 512 (writes into right half of hcat).
// ---------------------------------------------------------------------------
__global__ void agg_k(const float* __restrict__ t, const int* __restrict__ offsets,
                      const int* __restrict__ sorted_src, float* __restrict__ out, int n) {
    const int node = blockIdx.x * (blockDim.x >> 6) + (threadIdx.x >> 6);
    const int lane = threadIdx.x & 63;
    if (node >= n) return;
    const int lo = offsets[node];
    const int hi = offsets[node + 1];
    float4 acc = make_float4(0.f, 0.f, 0.f, 0.f);
    for (int i = lo; i < hi; i++) {
        int s = sorted_src[i];
        const float4 v = *reinterpret_cast<const float4*>(t + (size_t)s * 256 + lane * 4);
        acc.x += v.x; acc.y += v.y; acc.z += v.z; acc.w += v.w;
    }
    *reinterpret_cast<float4*>(out + (size_t)node * 512 + (size_t)lane * 4) = acc;
}

// ---------------------------------------------------------------------------
extern "C" void kernel_launch(void* const* d_in, const int* in_sizes, int n_in,
                              void* d_out, int out_size, void* d_ws, size_t ws_size,
                              hipStream_t stream) {
    const float* x       = (const float*)d_in[0];
    const int*   edges   = (const int*)d_in[1];
    const float* pre_w1  = (const float*)d_in[2];
    const float* pre_b1  = (const float*)d_in[3];
    const float* pre_w2  = (const float*)d_in[4];
    const float* pre_b2  = (const float*)d_in[5];
    const float* conv_w  = (const float*)d_in[6];
    const float* conv_b  = (const float*)d_in[7];
    const float* post_w1 = (const float*)d_in[8];
    const float* post_b1 = (const float*)d_in[9];
    const float* post_w2 = (const float*)d_in[10];
    const float* post_b2 = (const float*)d_in[11];

    const int N   = in_sizes[0] / 16;   // F_IN = 16
    const int E   = in_sizes[1] / 2;
    const int HID = 256;
    const int FO  = 16;
    const int* src = edges;
    const int* dst = edges + E;

    // workspace layout
    float* hcat = (float*)d_ws;                        // N x 512 (h || agg)
    float* bufA = hcat + (size_t)N * 512;              // N x 256 (t0 -> t -> z)
    int* offsets = (int*)(bufA + (size_t)N * 256);     // N+1
    int* counts  = offsets + (N + 1);                  // N
    int* cursor  = counts + N;                         // N
    int* sorted  = cursor + N;                         // E

    const dim3 blk(256);
    const dim3 g_big(HID / 64, (N + 127) / 128);

    // 1. t0 = relu(x @ pre_w1 + b1)
    gemm_k<128,64,16,8,4,1><<<g_big, blk, 0, stream>>>(x, 16, pre_w1, HID, pre_b1, bufA, HID, N, 16);
    // 2. h = t0 @ pre_w2 + b2 -> hcat[:, :256]
    gemm_k<128,64,16,8,4,0><<<g_big, blk, 0, stream>>>(bufA, HID, pre_w2, HID, pre_b2, hcat, 512, N, HID);
    // 3. t = relu(h @ conv_w + b) -> bufA
    gemm_k<128,64,16,8,4,1><<<g_big, blk, 0, stream>>>(hcat, 512, conv_w, HID, conv_b, bufA, HID, N, HID);

    // 4. CSR by destination + aggregate -> hcat[:, 256:]
    hipMemsetAsync(counts, 0, (size_t)N * sizeof(int), stream);
    hist_k<<<(E + 255) / 256, blk, 0, stream>>>(dst, E, counts);
    scan_k<<<1, 1024, 0, stream>>>(counts, offsets, cursor, N, E);
    fill_k<<<(E + 255) / 256, blk, 0, stream>>>(src, dst, E, cursor, sorted);
    agg_k<<<(N + 3) / 4, blk, 0, stream>>>(bufA, offsets, sorted, hcat + 256, N);

    // 5. z = relu(hcat @ post_w1 + b1) -> bufA
    gemm_k<128,64,16,8,4,1><<<g_big, blk, 0, stream>>>(hcat, 512, post_w1, HID, post_b1, bufA, HID, N, 512);
    // 6. out = tanh(z @ post_w2 + b2)
    gemm_k<64,16,16,4,1,2><<<dim3(1, (N + 63) / 64), blk, 0, stream>>>(bufA, HID, post_w2, FO, post_b2, (float*)d_out, FO, N, HID);
}

// Round 2
// 658.651 us; speedup vs baseline: 1.4286x; 1.4286x over previous
//
#include <hip/hip_runtime.h>
#include <hip/hip_bf16.h>

using s16x8 = __attribute__((ext_vector_type(8))) short;   // 8 bf16 (4 VGPRs)
using f32x4 = __attribute__((ext_vector_type(4))) float;
using u16 = unsigned short;

__device__ __forceinline__ u16 f2bf(float v) {             // RNE fp32 -> bf16
    unsigned u = __float_as_uint(v);
    return (u16)((u + 0x7fffu + ((u >> 16) & 1u)) >> 16);
}
__device__ __forceinline__ float bf2f(u16 h) {
    return __uint_as_float(((unsigned)h) << 16);
}

// ---------------------------------------------------------------------------
// bf16x3 MFMA GEMM: C = act(A @ B + bias), fp32-equivalent accuracy.
// A given as hi/lo bf16 pair, [M][K] row-major (lda elems).
// B given as hi/lo bf16 pair, TRANSPOSED: [Ncols][K] row-major.
// C: fp32 (OUTM=0) or hi/lo bf16 pair (OUTM=1), ldc elems.
// Block: 256 thr = 4 waves (2x2), tile 128x64, BK=32, mfma 16x16x32.
// ---------------------------------------------------------------------------
template<int ACT, int OUTM>
__global__ __launch_bounds__(256)
void mfma3_k(const u16* __restrict__ Ahi, const u16* __restrict__ Alo, int lda,
             const u16* __restrict__ BThi, const u16* __restrict__ BTlo,
             const float* __restrict__ bias,
             float* __restrict__ Cf, u16* __restrict__ Chi, u16* __restrict__ Clo,
             int ldc, int M, int K) {
    __shared__ u16 Ah[128 * 32], Al[128 * 32], Bh[64 * 32], Bl[64 * 32];  // 24 KB
    const int tid  = threadIdx.x;
    const int brow = blockIdx.y * 128;
    const int bcol = blockIdx.x * 64;
    const int lane = tid & 63;
    const int wid  = tid >> 6;
    const int wr = wid >> 1, wc = wid & 1;      // 2x2 wave grid, each 64x32
    const int lr = lane & 15, lq = lane >> 4;   // frag row/col, k-quarter

    f32x4 acc[4][2] = {};

    for (int k0 = 0; k0 < K; k0 += 32) {
        // stage A tile 128x32 (hi+lo), 16B chunks, XOR-swizzled chunk slot
        #pragma unroll
        for (int it = 0; it < 2; ++it) {
            int ch = tid + it * 256;            // 0..511
            int row = ch >> 2, c = ch & 3;
            int grow = brow + row;
            uint4 vh = make_uint4(0, 0, 0, 0), vl = make_uint4(0, 0, 0, 0);
            if (grow < M) {
                size_t off = (size_t)grow * lda + k0 + c * 8;
                vh = *reinterpret_cast<const uint4*>(Ahi + off);
                vl = *reinterpret_cast<const uint4*>(Alo + off);
            }
            int dst = row * 32 + ((c ^ (row & 3)) * 8);
            *reinterpret_cast<uint4*>(Ah + dst) = vh;
            *reinterpret_cast<uint4*>(Al + dst) = vl;
        }
        // stage B tile 64(cols)x32(k) from BT (hi+lo)
        {
            int row = tid >> 2, c = tid & 3;
            size_t off = (size_t)(bcol + row) * K + k0 + c * 8;
            int dst = row * 32 + ((c ^ (row & 3)) * 8);
            *reinterpret_cast<uint4*>(Bh + dst) = *reinterpret_cast<const uint4*>(BThi + off);
            *reinterpret_cast<uint4*>(Bl + dst) = *reinterpret_cast<const uint4*>(BTlo + off);
        }
        __syncthreads();

        s16x8 bh[2], bl[2];
        #pragma unroll
        for (int n = 0; n < 2; ++n) {
            int bc = wc * 32 + n * 16 + lr;
            int boff = bc * 32 + ((lq ^ (bc & 3)) * 8);
            bh[n] = *reinterpret_cast<const s16x8*>(Bh + boff);
            bl[n] = *reinterpret_cast<const s16x8*>(Bl + boff);
        }
        #pragma unroll
        for (int m = 0; m < 4; ++m) {
            int ar = wr * 64 + m * 16 + lr;
            int aoff = ar * 32 + ((lq ^ (ar & 3)) * 8);
            s16x8 ah = *reinterpret_cast<const s16x8*>(Ah + aoff);
            s16x8 al = *reinterpret_cast<const s16x8*>(Al + aoff);
            #pragma unroll
            for (int n = 0; n < 2; ++n) {
                acc[m][n] = __builtin_amdgcn_mfma_f32_16x16x32_bf16(ah, bh[n], acc[m][n], 0, 0, 0);
                acc[m][n] = __builtin_amdgcn_mfma_f32_16x16x32_bf16(ah, bl[n], acc[m][n], 0, 0, 0);
                acc[m][n] = __builtin_amdgcn_mfma_f32_16x16x32_bf16(al, bh[n], acc[m][n], 0, 0, 0);
            }
        }
        __syncthreads();
    }

    // epilogue: C[row=(lane>>4)*4+r][col=lane&15] per fragment (m89-verified)
    #pragma unroll
    for (int m = 0; m < 4; ++m) {
        #pragma unroll
        for (int n = 0; n < 2; ++n) {
            #pragma unroll
            for (int r = 0; r < 4; ++r) {
                int grow = brow + wr * 64 + m * 16 + lq * 4 + r;
                if (grow >= M) continue;
                int gcol = bcol + wc * 32 + n * 16 + lr;
                float v = acc[m][n][r] + bias[gcol];
                if (ACT == 1) v = fmaxf(v, 0.f);
                size_t o = (size_t)grow * ldc + gcol;
                if (OUTM == 0) {
                    Cf[o] = v;
                } else {
                    u16 h = f2bf(v);
                    Chi[o] = h;
                    Clo[o] = f2bf(v - bf2f(h));
                }
            }
        }
    }
}

// ---------------------------------------------------------------------------
// fp32 tiled GEMM (kept for the tiny final layer, N=16): C = act(A@B + bias)
// ---------------------------------------------------------------------------
template<int BM, int BN, int BK, int TM, int TN, int ACT>
__global__ __launch_bounds__((BM / TM) * (BN / TN))
void gemm_k(const float* __restrict__ A, int lda,
            const float* __restrict__ B, int ldb,
            const float* __restrict__ bias,
            float* __restrict__ C, int ldc,
            int N, int K) {
    constexpr int THREADS = (BM / TM) * (BN / TN);
    __shared__ float As[BK][BM];
    __shared__ float Bs[BK][BN + 4];
    const int tid  = threadIdx.x;
    const int brow = blockIdx.y * BM;
    const int bcol = blockIdx.x * BN;
    constexpr int TCOLS = BN / TN;
    const int tcol = tid % TCOLS;
    const int trow = tid / TCOLS;
    float acc[TM][TN] = {};
    for (int k0 = 0; k0 < K; k0 += BK) {
        #pragma unroll
        for (int i = tid; i < BM * BK; i += THREADS) {
            int r = i / BK, c = i % BK;
            int gr = brow + r;
            As[c][r] = (gr < N) ? A[(size_t)gr * lda + (k0 + c)] : 0.f;
        }
        #pragma unroll
        for (int i = tid; i < BK * BN; i += THREADS) {
            int r = i / BN, c = i % BN;
            Bs[r][c] = B[(size_t)(k0 + r) * ldb + (bcol + c)];
        }
        __syncthreads();
        #pragma unroll
        for (int kk = 0; kk < BK; kk++) {
            float a[TM], b[TN];
            #pragma unroll
            for (int m = 0; m < TM; m++) a[m] = As[kk][trow * TM + m];
            #pragma unroll
            for (int n = 0; n < TN; n++) b[n] = Bs[kk][tcol * TN + n];
            #pragma unroll
            for (int m = 0; m < TM; m++)
                #pragma unroll
                for (int n = 0; n < TN; n++)
                    acc[m][n] = fmaf(a[m], b[n], acc[m][n]);
        }
        __syncthreads();
    }
    #pragma unroll
    for (int m = 0; m < TM; m++) {
        int gr = brow + trow * TM + m;
        if (gr >= N) continue;
        #pragma unroll
        for (int n = 0; n < TN; n++) {
            int gc = bcol + tcol * TN + n;
            float v = acc[m][n] + bias[gc];
            if (ACT == 1) v = fmaxf(v, 0.f);
            else if (ACT == 2) v = tanhf(v);
            C[(size_t)gr * ldc + gc] = v;
        }
    }
}

// ---------------------------------------------------------------------------
// Layer 1 (K=16) fused with hi/lo split epilogue
// ---------------------------------------------------------------------------
__global__ __launch_bounds__(256)
void pre1_k(const float* __restrict__ x, const float* __restrict__ w1,
            const float* __restrict__ b1,
            u16* __restrict__ t0hi, u16* __restrict__ t0lo, int M) {
    __shared__ float ws[16 * 256];
    __shared__ float xs[16][17];
    const int tid = threadIdx.x;
    for (int i = tid; i < 16 * 256; i += 256) ws[i] = w1[i];
    const int r0 = blockIdx.x * 16;
    {
        int rr = tid >> 4, cc = tid & 15;
        xs[rr][cc] = (r0 + rr < M) ? x[(size_t)(r0 + rr) * 16 + cc] : 0.f;
    }
    __syncthreads();
    const int c = tid;
    const float b = b1[c];
    for (int r = 0; r < 16; r++) {
        if (r0 + r >= M) break;
        float acc = b;
        #pragma unroll
        for (int k = 0; k < 16; k++) acc = fmaf(xs[r][k], ws[k * 256 + c], acc);
        acc = fmaxf(acc, 0.f);
        u16 h = f2bf(acc);
        t0hi[(size_t)(r0 + r) * 256 + c] = h;
        t0lo[(size_t)(r0 + r) * 256 + c] = f2bf(acc - bf2f(h));
    }
}

// weight split + transpose: W [K][N] fp32 -> hiT/loT [N][K] bf16
__global__ void wsplit_k(const float* __restrict__ W, u16* __restrict__ hiT,
                         u16* __restrict__ loT, int K, int N) {
    int i = blockIdx.x * blockDim.x + threadIdx.x;
    if (i >= K * N) return;
    int n = i / K, k = i % K;
    float v = W[(size_t)k * N + n];
    u16 h = f2bf(v);
    hiT[i] = h;
    loT[i] = f2bf(v - bf2f(h));
}

// ---------------------------------------------------------------------------
// CSR-by-destination build
// ---------------------------------------------------------------------------
__global__ void hist_k(const int* __restrict__ dst, int E, int* __restrict__ counts) {
    int i = blockIdx.x * blockDim.x + threadIdx.x;
    if (i < E) atomicAdd(&counts[dst[i]], 1);
}

__global__ void scan_k(const int* __restrict__ counts, int* __restrict__ offsets,
                       int* __restrict__ cursor, int n, int total) {
    __shared__ int sh[1024];
    const int t = threadIdx.x;
    const int chunk = (n + 1023) >> 10;
    const int lo = t * chunk;
    const int hi = min(lo + chunk, n);
    int s = 0;
    for (int i = lo; i < hi; i++) s += counts[i];
    sh[t] = s;
    __syncthreads();
    #pragma unroll
    for (int d = 1; d < 1024; d <<= 1) {
        int v = (t >= d) ? sh[t - d] : 0;
        __syncthreads();
        sh[t] += v;
        __syncthreads();
    }
    int off = sh[t] - s;
    for (int i = lo; i < hi; i++) {
        offsets[i] = off;
        cursor[i]  = off;
        off += counts[i];
    }
    if (t == 0) offsets[n] = total;
}

__global__ void fill_k(const int* __restrict__ src, const int* __restrict__ dst, int E,
                       int* __restrict__ cursor, int* __restrict__ sorted_src) {
    int i = blockIdx.x * blockDim.x + threadIdx.x;
    if (i < E) {
        int d = dst[i];
        int pos = atomicAdd(&cursor[d], 1);
        sorted_src[pos] = src[i];
    }
}

// ---------------------------------------------------------------------------
// Aggregate incoming messages (fp32 accumulate), write hi/lo bf16 into
// hcat columns 256..511 (row stride 512).
// ---------------------------------------------------------------------------
__global__ void agg_k(const float* __restrict__ t, const int* __restrict__ offsets,
                      const int* __restrict__ sorted_src,
                      u16* __restrict__ hi, u16* __restrict__ lo, int n) {
    const int node = blockIdx.x * (blockDim.x >> 6) + (threadIdx.x >> 6);
    const int lane = threadIdx.x & 63;
    if (node >= n) return;
    const int s0 = offsets[node], s1 = offsets[node + 1];
    float4 acc = make_float4(0.f, 0.f, 0.f, 0.f);
    for (int i = s0; i < s1; i++) {
        int s = sorted_src[i];
        const float4 v = *reinterpret_cast<const float4*>(t + (size_t)s * 256 + lane * 4);
        acc.x += v.x; acc.y += v.y; acc.z += v.z; acc.w += v.w;
    }
    ushort4 h4, l4;
    h4.x = f2bf(acc.x); l4.x = f2bf(acc.x - bf2f(h4.x));
    h4.y = f2bf(acc.y); l4.y = f2bf(acc.y - bf2f(h4.y));
    h4.z = f2bf(acc.z); l4.z = f2bf(acc.z - bf2f(h4.z));
    h4.w = f2bf(acc.w); l4.w = f2bf(acc.w - bf2f(h4.w));
    size_t o = (size_t)node * 512 + 256 + (size_t)lane * 4;
    *reinterpret_cast<ushort4*>(hi + o) = h4;
    *reinterpret_cast<ushort4*>(lo + o) = l4;
}

// ---------------------------------------------------------------------------
extern "C" void kernel_launch(void* const* d_in, const int* in_sizes, int n_in,
                              void* d_out, int out_size, void* d_ws, size_t ws_size,
                              hipStream_t stream) {
    const float* x       = (const float*)d_in[0];
    const int*   edges   = (const int*)d_in[1];
    const float* pre_w1  = (const float*)d_in[2];
    const float* pre_b1  = (const float*)d_in[3];
    const float* pre_w2  = (const float*)d_in[4];
    const float* pre_b2  = (const float*)d_in[5];
    const float* conv_w  = (const float*)d_in[6];
    const float* conv_b  = (const float*)d_in[7];
    const float* post_w1 = (const float*)d_in[8];
    const float* post_b1 = (const float*)d_in[9];
    const float* post_w2 = (const float*)d_in[10];
    const float* post_b2 = (const float*)d_in[11];

    const int N = in_sizes[0] / 16;
    const int E = in_sizes[1] / 2;
    const int* src = edges;
    const int* dst = edges + E;

    // workspace layout (~158.5 MB)
    u16*   hcat_hi = (u16*)d_ws;                           // N x 512
    u16*   hcat_lo = hcat_hi + (size_t)N * 512;            // N x 512
    float* Cbuf    = (float*)(hcat_lo + (size_t)N * 512);  // N x 256 f32 (t, then z)
    u16*   t0hi    = (u16*)Cbuf;                           // alias: t0 lives before t
    u16*   t0lo    = t0hi + (size_t)N * 256;
    u16*   w2hi    = (u16*)(Cbuf + (size_t)N * 256);
    u16*   w2lo    = w2hi + 256 * 256;
    u16*   cvhi    = w2lo + 256 * 256;
    u16*   cvlo    = cvhi + 256 * 256;
    u16*   p1hi    = cvlo + 256 * 256;
    u16*   p1lo    = p1hi + 512 * 256;
    int* offsets = (int*)(p1lo + 512 * 256);               // N+1
    int* counts  = offsets + (N + 1);                      // N
    int* cursor  = counts + N;                             // N
    int* sorted  = cursor + N;                             // E

    const dim3 blk(256);
    const dim3 g_mfma(256 / 64, (N + 127) / 128);

    // weight splits (transposed)
    wsplit_k<<<(256 * 256 + 255) / 256, blk, 0, stream>>>(pre_w2, w2hi, w2lo, 256, 256);
    wsplit_k<<<(256 * 256 + 255) / 256, blk, 0, stream>>>(conv_w, cvhi, cvlo, 256, 256);
    wsplit_k<<<(512 * 256 + 255) / 256, blk, 0, stream>>>(post_w1, p1hi, p1lo, 512, 256);

    // CSR by destination (independent of GEMMs)
    hipMemsetAsync(counts, 0, (size_t)N * sizeof(int), stream);
    hist_k<<<(E + 255) / 256, blk, 0, stream>>>(dst, E, counts);
    scan_k<<<1, 1024, 0, stream>>>(counts, offsets, cursor, N, E);
    fill_k<<<(E + 255) / 256, blk, 0, stream>>>(src, dst, E, cursor, sorted);

    // 1. t0 = relu(x @ pre_w1 + b1), split hi/lo
    pre1_k<<<(N + 15) / 16, blk, 0, stream>>>(x, pre_w1, pre_b1, t0hi, t0lo, N);
    // 2. h = t0 @ pre_w2 + b2 -> hcat[:, :256] (hi/lo)
    mfma3_k<0, 1><<<g_mfma, blk, 0, stream>>>(t0hi, t0lo, 256, w2hi, w2lo, pre_b2,
                                              nullptr, hcat_hi, hcat_lo, 512, N, 256);
    // 3. t = relu(h @ conv_w + cb) -> Cbuf fp32
    mfma3_k<1, 0><<<g_mfma, blk, 0, stream>>>(hcat_hi, hcat_lo, 512, cvhi, cvlo, conv_b,
                                              Cbuf, nullptr, nullptr, 256, N, 256);
    // 4. aggregate -> hcat[:, 256:] (hi/lo)
    agg_k<<<(N + 3) / 4, blk, 0, stream>>>(Cbuf, offsets, sorted, hcat_hi, hcat_lo, N);
    // 5. z = relu(hcat @ post_w1 + b1) -> Cbuf fp32 (t dead)
    mfma3_k<1, 0><<<g_mfma, blk, 0, stream>>>(hcat_hi, hcat_lo, 512, p1hi, p1lo, post_b1,
                                              Cbuf, nullptr, nullptr, 256, N, 512);
    // 6. out = tanh(z @ post_w2 + b2), fp32 exact final layer
    gemm_k<64, 16, 16, 4, 1, 2><<<dim3(1, (N + 63) / 64), blk, 0, stream>>>(
        Cbuf, 256, post_w2, 16, post_b2, (float*)d_out, 16, N, 256);
}

// Round 3
// 552.642 us; speedup vs baseline: 1.7027x; 1.1918x over previous
//
#include <hip/hip_runtime.h>
#include <hip/hip_bf16.h>

using s16x8 = __attribute__((ext_vector_type(8))) short;   // 8 bf16 (4 VGPRs)
using f32x4 = __attribute__((ext_vector_type(4))) float;
using u16 = unsigned short;

__device__ __forceinline__ u16 f2bf(float v) {             // RNE fp32 -> bf16
    unsigned u = __float_as_uint(v);
    return (u16)((u + 0x7fffu + ((u >> 16) & 1u)) >> 16);
}
__device__ __forceinline__ float bf2f(u16 h) {
    return __uint_as_float(((unsigned)h) << 16);
}

// ---------------------------------------------------------------------------
// bf16x3 MFMA GEMM, tile 128 rows x 256 cols (full width), K-step 32.
// 512 threads = 8 waves in 2x4 grid; each wave owns a 64x64 output tile.
// A hi/lo [M][K] row-major (lda); B hi/lo transposed [256][K] row-major.
// C: fp32 (OUTM=0) or hi/lo bf16 pair (OUTM=1).
// Pipeline: reg-staged global loads for tile t+1 issued before compute of
// tile t; LDS double-buffered; ONE barrier per K-step.
// ---------------------------------------------------------------------------
template<int ACT, int OUTM>
__global__ __launch_bounds__(512)
void mfma3_k(const u16* __restrict__ Ahi, const u16* __restrict__ Alo, int lda,
             const u16* __restrict__ BThi, const u16* __restrict__ BTlo,
             const float* __restrict__ bias,
             float* __restrict__ Cf, u16* __restrict__ Chi, u16* __restrict__ Clo,
             int ldc, int M, int K) {
    __shared__ u16 Ah[2][128 * 32];   // 16 KB
    __shared__ u16 Al[2][128 * 32];   // 16 KB
    __shared__ u16 Bh[2][256 * 32];   // 32 KB
    __shared__ u16 Bl[2][256 * 32];   // 32 KB   (total 96 KB)

    const int tid  = threadIdx.x;
    const int brow = blockIdx.x * 128;
    const int lane = tid & 63;
    const int wid  = tid >> 6;
    const int wr = wid >> 2, wc = wid & 3;      // 2x4 wave grid
    const int lr = lane & 15, lq = lane >> 4;

    // ---- staging addresses (fixed per thread; advance by k) ----
    const int arow = tid >> 2;                  // 0..127
    const int ac   = tid & 3;                   // 8-elem chunk within 32-k
    const int adst = arow * 32 + ((ac ^ (arow & 3)) * 8);
    const int agrow = brow + arow;
    const bool aval = (agrow < M);
    const u16* pAh = Ahi + (size_t)agrow * lda + ac * 8;
    const u16* pAl = Alo + (size_t)agrow * lda + ac * 8;

    const int br0 = tid >> 2;                   // B rows 0..127
    const int br1 = 128 + br0;                  // B rows 128..255
    const int bdst0 = br0 * 32 + ((ac ^ (br0 & 3)) * 8);
    const int bdst1 = br1 * 32 + ((ac ^ (br1 & 3)) * 8);
    const u16* pBh0 = BThi + (size_t)br0 * K + ac * 8;
    const u16* pBh1 = BThi + (size_t)br1 * K + ac * 8;
    const u16* pBl0 = BTlo + (size_t)br0 * K + ac * 8;
    const u16* pBl1 = BTlo + (size_t)br1 * K + ac * 8;

    uint4 rAh, rAl, rBh0, rBh1, rBl0, rBl1;
    const uint4 z4 = make_uint4(0, 0, 0, 0);

#define LOADT(k0)                                                              \
    do {                                                                       \
        if (aval) {                                                            \
            rAh = *reinterpret_cast<const uint4*>(pAh + (k0));                 \
            rAl = *reinterpret_cast<const uint4*>(pAl + (k0));                 \
        } else { rAh = z4; rAl = z4; }                                         \
        rBh0 = *reinterpret_cast<const uint4*>(pBh0 + (k0));                   \
        rBh1 = *reinterpret_cast<const uint4*>(pBh1 + (k0));                   \
        rBl0 = *reinterpret_cast<const uint4*>(pBl0 + (k0));                   \
        rBl1 = *reinterpret_cast<const uint4*>(pBl1 + (k0));                   \
    } while (0)

#define WRITET(b)                                                              \
    do {                                                                       \
        *reinterpret_cast<uint4*>(&Ah[b][adst])  = rAh;                        \
        *reinterpret_cast<uint4*>(&Al[b][adst])  = rAl;                        \
        *reinterpret_cast<uint4*>(&Bh[b][bdst0]) = rBh0;                       \
        *reinterpret_cast<uint4*>(&Bh[b][bdst1]) = rBh1;                       \
        *reinterpret_cast<uint4*>(&Bl[b][bdst0]) = rBl0;                       \
        *reinterpret_cast<uint4*>(&Bl[b][bdst1]) = rBl1;                       \
    } while (0)

    f32x4 acc[4][4] = {};

    LOADT(0);
    WRITET(0);
    __syncthreads();

    const int nt = K >> 5;
    int cur = 0;
    for (int t = 0; t < nt; ++t) {
        if (t + 1 < nt) LOADT((t + 1) << 5);

        s16x8 bhf[4], blf[4];
        #pragma unroll
        for (int n = 0; n < 4; ++n) {
            int bc = wc * 64 + n * 16 + lr;
            int boff = bc * 32 + ((lq ^ (bc & 3)) * 8);
            bhf[n] = *reinterpret_cast<const s16x8*>(&Bh[cur][boff]);
            blf[n] = *reinterpret_cast<const s16x8*>(&Bl[cur][boff]);
        }
        #pragma unroll
        for (int m = 0; m < 4; ++m) {
            int ar = wr * 64 + m * 16 + lr;
            int aoff = ar * 32 + ((lq ^ (ar & 3)) * 8);
            s16x8 ah = *reinterpret_cast<const s16x8*>(&Ah[cur][aoff]);
            s16x8 al = *reinterpret_cast<const s16x8*>(&Al[cur][aoff]);
            #pragma unroll
            for (int n = 0; n < 4; ++n) {
                acc[m][n] = __builtin_amdgcn_mfma_f32_16x16x32_bf16(ah, bhf[n], acc[m][n], 0, 0, 0);
                acc[m][n] = __builtin_amdgcn_mfma_f32_16x16x32_bf16(ah, blf[n], acc[m][n], 0, 0, 0);
                acc[m][n] = __builtin_amdgcn_mfma_f32_16x16x32_bf16(al, bhf[n], acc[m][n], 0, 0, 0);
            }
        }

        if (t + 1 < nt) {
            WRITET(cur ^ 1);      // compiler inserts vmcnt before ds_writes
            __syncthreads();      // single barrier per K-step
            cur ^= 1;
        }
    }
#undef LOADT
#undef WRITET

    // epilogue: frag layout col=lane&15, row=(lane>>4)*4+r (m89-verified)
    #pragma unroll
    for (int m = 0; m < 4; ++m) {
        #pragma unroll
        for (int n = 0; n < 4; ++n) {
            #pragma unroll
            for (int r = 0; r < 4; ++r) {
                int grow = brow + wr * 64 + m * 16 + lq * 4 + r;
                if (grow >= M) continue;
                int gcol = wc * 64 + n * 16 + lr;
                float v = acc[m][n][r] + bias[gcol];
                if (ACT == 1) v = fmaxf(v, 0.f);
                size_t o = (size_t)grow * ldc + gcol;
                if (OUTM == 0) {
                    Cf[o] = v;
                } else {
                    u16 h = f2bf(v);
                    Chi[o] = h;
                    Clo[o] = f2bf(v - bf2f(h));
                }
            }
        }
    }
}

// ---------------------------------------------------------------------------
// fp32 tiled GEMM (final tiny layer, N=16): C = act(A@B + bias)
// ---------------------------------------------------------------------------
template<int BM, int BN, int BK, int TM, int TN, int ACT>
__global__ __launch_bounds__((BM / TM) * (BN / TN))
void gemm_k(const float* __restrict__ A, int lda,
            const float* __restrict__ B, int ldb,
            const float* __restrict__ bias,
            float* __restrict__ C, int ldc,
            int N, int K) {
    constexpr int THREADS = (BM / TM) * (BN / TN);
    __shared__ float As[BK][BM];
    __shared__ float Bs[BK][BN + 4];
    const int tid  = threadIdx.x;
    const int brow = blockIdx.y * BM;
    const int bcol = blockIdx.x * BN;
    constexpr int TCOLS = BN / TN;
    const int tcol = tid % TCOLS;
    const int trow = tid / TCOLS;
    float acc[TM][TN] = {};
    for (int k0 = 0; k0 < K; k0 += BK) {
        #pragma unroll
        for (int i = tid; i < BM * BK; i += THREADS) {
            int r = i / BK, c = i % BK;
            int gr = brow + r;
            As[c][r] = (gr < N) ? A[(size_t)gr * lda + (k0 + c)] : 0.f;
        }
        #pragma unroll
        for (int i = tid; i < BK * BN; i += THREADS) {
            int r = i / BN, c = i % BN;
            Bs[r][c] = B[(size_t)(k0 + r) * ldb + (bcol + c)];
        }
        __syncthreads();
        #pragma unroll
        for (int kk = 0; kk < BK; kk++) {
            float a[TM], b[TN];
            #pragma unroll
            for (int m = 0; m < TM; m++) a[m] = As[kk][trow * TM + m];
            #pragma unroll
            for (int n = 0; n < TN; n++) b[n] = Bs[kk][tcol * TN + n];
            #pragma unroll
            for (int m = 0; m < TM; m++)
                #pragma unroll
                for (int n = 0; n < TN; n++)
                    acc[m][n] = fmaf(a[m], b[n], acc[m][n]);
        }
        __syncthreads();
    }
    #pragma unroll
    for (int m = 0; m < TM; m++) {
        int gr = brow + trow * TM + m;
        if (gr >= N) continue;
        #pragma unroll
        for (int n = 0; n < TN; n++) {
            int gc = bcol + tcol * TN + n;
            float v = acc[m][n] + bias[gc];
            if (ACT == 1) v = fmaxf(v, 0.f);
            else if (ACT == 2) v = tanhf(v);
            C[(size_t)gr * ldc + gc] = v;
        }
    }
}

// ---------------------------------------------------------------------------
// Layer 1 (K=16) fused with hi/lo split epilogue
// ---------------------------------------------------------------------------
__global__ __launch_bounds__(256)
void pre1_k(const float* __restrict__ x, const float* __restrict__ w1,
            const float* __restrict__ b1,
            u16* __restrict__ t0hi, u16* __restrict__ t0lo, int M) {
    __shared__ float ws[16 * 256];
    __shared__ float xs[16][17];
    const int tid = threadIdx.x;
    for (int i = tid; i < 16 * 256; i += 256) ws[i] = w1[i];
    const int r0 = blockIdx.x * 16;
    {
        int rr = tid >> 4, cc = tid & 15;
        xs[rr][cc] = (r0 + rr < M) ? x[(size_t)(r0 + rr) * 16 + cc] : 0.f;
    }
    __syncthreads();
    const int c = tid;
    const float b = b1[c];
    for (int r = 0; r < 16; r++) {
        if (r0 + r >= M) break;
        float acc = b;
        #pragma unroll
        for (int k = 0; k < 16; k++) acc = fmaf(xs[r][k], ws[k * 256 + c], acc);
        acc = fmaxf(acc, 0.f);
        u16 h = f2bf(acc);
        t0hi[(size_t)(r0 + r) * 256 + c] = h;
        t0lo[(size_t)(r0 + r) * 256 + c] = f2bf(acc - bf2f(h));
    }
}

// weight split + transpose: W [K][N] fp32 -> hiT/loT [N][K] bf16
__global__ void wsplit_k(const float* __restrict__ W, u16* __restrict__ hiT,
                         u16* __restrict__ loT, int K, int N) {
    int i = blockIdx.x * blockDim.x + threadIdx.x;
    if (i >= K * N) return;
    int n = i / K, k = i % K;
    float v = W[(size_t)k * N + n];
    u16 h = f2bf(v);
    hiT[i] = h;
    loT[i] = f2bf(v - bf2f(h));
}

// ---------------------------------------------------------------------------
// CSR-by-destination build
// ---------------------------------------------------------------------------
__global__ void hist_k(const int* __restrict__ dst, int E, int* __restrict__ counts) {
    int i = blockIdx.x * blockDim.x + threadIdx.x;
    if (i < E) atomicAdd(&counts[dst[i]], 1);
}

__global__ void scan_k(const int* __restrict__ counts, int* __restrict__ offsets,
                       int* __restrict__ cursor, int n, int total) {
    __shared__ int sh[1024];
    const int t = threadIdx.x;
    const int chunk = (n + 1023) >> 10;
    const int lo = t * chunk;
    const int hi = min(lo + chunk, n);
    int s = 0;
    for (int i = lo; i < hi; i++) s += counts[i];
    sh[t] = s;
    __syncthreads();
    #pragma unroll
    for (int d = 1; d < 1024; d <<= 1) {
        int v = (t >= d) ? sh[t - d] : 0;
        __syncthreads();
        sh[t] += v;
        __syncthreads();
    }
    int off = sh[t] - s;
    for (int i = lo; i < hi; i++) {
        offsets[i] = off;
        cursor[i]  = off;
        off += counts[i];
    }
    if (t == 0) offsets[n] = total;
}

__global__ void fill_k(const int* __restrict__ src, const int* __restrict__ dst, int E,
                       int* __restrict__ cursor, int* __restrict__ sorted_src) {
    int i = blockIdx.x * blockDim.x + threadIdx.x;
    if (i < E) {
        int d = dst[i];
        int pos = atomicAdd(&cursor[d], 1);
        sorted_src[pos] = src[i];
    }
}

// ---------------------------------------------------------------------------
// Aggregate incoming messages (fp32 accumulate), write hi/lo bf16 into
// hcat columns 256..511 (row stride 512).
// ---------------------------------------------------------------------------
__global__ void agg_k(const float* __restrict__ t, const int* __restrict__ offsets,
                      const int* __restrict__ sorted_src,
                      u16* __restrict__ hi, u16* __restrict__ lo, int n) {
    const int node = blockIdx.x * (blockDim.x >> 6) + (threadIdx.x >> 6);
    const int lane = threadIdx.x & 63;
    if (node >= n) return;
    const int s0 = offsets[node], s1 = offsets[node + 1];
    float4 acc = make_float4(0.f, 0.f, 0.f, 0.f);
    for (int i = s0; i < s1; i++) {
        int s = sorted_src[i];
        const float4 v = *reinterpret_cast<const float4*>(t + (size_t)s * 256 + lane * 4);
        acc.x += v.x; acc.y += v.y; acc.z += v.z; acc.w += v.w;
    }
    ushort4 h4, l4;
    h4.x = f2bf(acc.x); l4.x = f2bf(acc.x - bf2f(h4.x));
    h4.y = f2bf(acc.y); l4.y = f2bf(acc.y - bf2f(h4.y));
    h4.z = f2bf(acc.z); l4.z = f2bf(acc.z - bf2f(h4.z));
    h4.w = f2bf(acc.w); l4.w = f2bf(acc.w - bf2f(h4.w));
    size_t o = (size_t)node * 512 + 256 + (size_t)lane * 4;
    *reinterpret_cast<ushort4*>(hi + o) = h4;
    *reinterpret_cast<ushort4*>(lo + o) = l4;
}

// ---------------------------------------------------------------------------
extern "C" void kernel_launch(void* const* d_in, const int* in_sizes, int n_in,
                              void* d_out, int out_size, void* d_ws, size_t ws_size,
                              hipStream_t stream) {
    const float* x       = (const float*)d_in[0];
    const int*   edges   = (const int*)d_in[1];
    const float* pre_w1  = (const float*)d_in[2];
    const float* pre_b1  = (const float*)d_in[3];
    const float* pre_w2  = (const float*)d_in[4];
    const float* pre_b2  = (const float*)d_in[5];
    const float* conv_w  = (const float*)d_in[6];
    const float* conv_b  = (const float*)d_in[7];
    const float* post_w1 = (const float*)d_in[8];
    const float* post_b1 = (const float*)d_in[9];
    const float* post_w2 = (const float*)d_in[10];
    const float* post_b2 = (const float*)d_in[11];

    const int N = in_sizes[0] / 16;
    const int E = in_sizes[1] / 2;
    const int* src = edges;
    const int* dst = edges + E;

    // workspace layout (~160 MB)
    u16*   hcat_hi = (u16*)d_ws;                           // N x 512
    u16*   hcat_lo = hcat_hi + (size_t)N * 512;            // N x 512
    float* Cbuf    = (float*)(hcat_lo + (size_t)N * 512);  // N x 256 f32 (t, then z)
    u16*   t0hi    = (u16*)Cbuf;                           // alias: t0 dead before t written
    u16*   t0lo    = t0hi + (size_t)N * 256;
    u16*   w2hi    = (u16*)(Cbuf + (size_t)N * 256);
    u16*   w2lo    = w2hi + 256 * 256;
    u16*   cvhi    = w2lo + 256 * 256;
    u16*   cvlo    = cvhi + 256 * 256;
    u16*   p1hi    = cvlo + 256 * 256;
    u16*   p1lo    = p1hi + 512 * 256;
    int* offsets = (int*)(p1lo + 512 * 256);               // N+1
    int* counts  = offsets + (N + 1);                      // N
    int* cursor  = counts + N;                             // N
    int* sorted  = cursor + N;                             // E

    const dim3 blk(256);
    const dim3 g_mfma((N + 127) / 128);
    const dim3 blk_mfma(512);

    // weight splits (transposed)
    wsplit_k<<<(256 * 256 + 255) / 256, blk, 0, stream>>>(pre_w2, w2hi, w2lo, 256, 256);
    wsplit_k<<<(256 * 256 + 255) / 256, blk, 0, stream>>>(conv_w, cvhi, cvlo, 256, 256);
    wsplit_k<<<(512 * 256 + 255) / 256, blk, 0, stream>>>(post_w1, p1hi, p1lo, 512, 256);

    // CSR by destination (independent of GEMMs)
    hipMemsetAsync(counts, 0, (size_t)N * sizeof(int), stream);
    hist_k<<<(E + 255) / 256, blk, 0, stream>>>(dst, E, counts);
    scan_k<<<1, 1024, 0, stream>>>(counts, offsets, cursor, N, E);
    fill_k<<<(E + 255) / 256, blk, 0, stream>>>(src, dst, E, cursor, sorted);

    // 1. t0 = relu(x @ pre_w1 + b1), split hi/lo
    pre1_k<<<(N + 15) / 16, blk, 0, stream>>>(x, pre_w1, pre_b1, t0hi, t0lo, N);
    // 2. h = t0 @ pre_w2 + b2 -> hcat[:, :256] (hi/lo)
    mfma3_k<0, 1><<<g_mfma, blk_mfma, 0, stream>>>(t0hi, t0lo, 256, w2hi, w2lo, pre_b2,
                                                   nullptr, hcat_hi, hcat_lo, 512, N, 256);
    // 3. t = relu(h @ conv_w + cb) -> Cbuf fp32
    mfma3_k<1, 0><<<g_mfma, blk_mfma, 0, stream>>>(hcat_hi, hcat_lo, 512, cvhi, cvlo, conv_b,
                                                   Cbuf, nullptr, nullptr, 256, N, 256);
    // 4. aggregate -> hcat[:, 256:] (hi/lo)
    agg_k<<<(N + 3) / 4, blk, 0, stream>>>(Cbuf, offsets, sorted, hcat_hi, hcat_lo, N);
    // 5. z = relu(hcat @ post_w1 + b1) -> Cbuf fp32 (t dead)
    mfma3_k<1, 0><<<g_mfma, blk_mfma, 0, stream>>>(hcat_hi, hcat_lo, 512, p1hi, p1lo, post_b1,
                                                   Cbuf, nullptr, nullptr, 256, N, 512);
    // 6. out = tanh(z @ post_w2 + b2), fp32 exact final layer
    gemm_k<64, 16, 16, 4, 1, 2><<<dim3(1, (N + 63) / 64), blk, 0, stream>>>(
        Cbuf, 256, post_w2, 16, post_b2, (float*)d_out, 16, N, 256);
}

// Round 4
// 495.407 us; speedup vs baseline: 1.8994x; 1.1155x over previous
//
#include <hip/hip_runtime.h>
#include <hip/hip_bf16.h>

using s16x8 = __attribute__((ext_vector_type(8))) short;   // 8 bf16 (4 VGPRs)
using f32x4 = __attribute__((ext_vector_type(4))) float;
using u16 = unsigned short;

__device__ __forceinline__ u16 f2bf(float v) {             // RNE fp32 -> bf16
    unsigned u = __float_as_uint(v);
    return (u16)((u + 0x7fffu + ((u >> 16) & 1u)) >> 16);
}
__device__ __forceinline__ float bf2f(u16 h) {
    return __uint_as_float(((unsigned)h) << 16);
}
__device__ __forceinline__ u16 f2h(float v) {              // fp32 -> fp16 RNE
    _Float16 h = (_Float16)v;
    u16 r; __builtin_memcpy(&r, &h, 2); return r;
}
__device__ __forceinline__ float h2f(u16 x) {
    _Float16 h; __builtin_memcpy(&h, &x, 2); return (float)h;
}

// ---------------------------------------------------------------------------
// bf16x3 MFMA GEMM, tile 128 rows x 256 cols (full width), K-step 32.
// 512 threads = 8 waves (2x4); each wave owns a 64x64 output tile.
// A hi/lo [M][K] row-major (lda); B hi/lo transposed [256][K] row-major.
// OUTM: 0 = fp32 Cf, 1 = bf16 hi/lo pair, 2 = fp16 (u16) into Chi.
// Reg-staged global loads for t+1 before compute of t; LDS dbuf; 1 barrier.
// ---------------------------------------------------------------------------
template<int ACT, int OUTM>
__global__ __launch_bounds__(512)
void mfma3_k(const u16* __restrict__ Ahi, const u16* __restrict__ Alo, int lda,
             const u16* __restrict__ BThi, const u16* __restrict__ BTlo,
             const float* __restrict__ bias,
             float* __restrict__ Cf, u16* __restrict__ Chi, u16* __restrict__ Clo,
             int ldc, int M, int K) {
    __shared__ u16 Ah[2][128 * 32];
    __shared__ u16 Al[2][128 * 32];
    __shared__ u16 Bh[2][256 * 32];
    __shared__ u16 Bl[2][256 * 32];   // total 96 KB

    const int tid  = threadIdx.x;
    const int brow = blockIdx.x * 128;
    const int lane = tid & 63;
    const int wid  = tid >> 6;
    const int wr = wid >> 2, wc = wid & 3;      // 2x4 wave grid
    const int lr = lane & 15, lq = lane >> 4;

    const int arow = tid >> 2;                  // 0..127
    const int ac   = tid & 3;                   // 8-elem chunk within 32-k
    const int adst = arow * 32 + ((ac ^ (arow & 3)) * 8);
    const int agrow = brow + arow;
    const bool aval = (agrow < M);
    const u16* pAh = Ahi + (size_t)agrow * lda + ac * 8;
    const u16* pAl = Alo + (size_t)agrow * lda + ac * 8;

    const int br0 = tid >> 2;
    const int br1 = 128 + br0;
    const int bdst0 = br0 * 32 + ((ac ^ (br0 & 3)) * 8);
    const int bdst1 = br1 * 32 + ((ac ^ (br1 & 3)) * 8);
    const u16* pBh0 = BThi + (size_t)br0 * K + ac * 8;
    const u16* pBh1 = BThi + (size_t)br1 * K + ac * 8;
    const u16* pBl0 = BTlo + (size_t)br0 * K + ac * 8;
    const u16* pBl1 = BTlo + (size_t)br1 * K + ac * 8;

    uint4 rAh, rAl, rBh0, rBh1, rBl0, rBl1;
    const uint4 z4 = make_uint4(0, 0, 0, 0);

#define LOADT(k0)                                                              \
    do {                                                                       \
        if (aval) {                                                            \
            rAh = *reinterpret_cast<const uint4*>(pAh + (k0));                 \
            rAl = *reinterpret_cast<const uint4*>(pAl + (k0));                 \
        } else { rAh = z4; rAl = z4; }                                         \
        rBh0 = *reinterpret_cast<const uint4*>(pBh0 + (k0));                   \
        rBh1 = *reinterpret_cast<const uint4*>(pBh1 + (k0));                   \
        rBl0 = *reinterpret_cast<const uint4*>(pBl0 + (k0));                   \
        rBl1 = *reinterpret_cast<const uint4*>(pBl1 + (k0));                   \
    } while (0)

#define WRITET(b)                                                              \
    do {                                                                       \
        *reinterpret_cast<uint4*>(&Ah[b][adst])  = rAh;                        \
        *reinterpret_cast<uint4*>(&Al[b][adst])  = rAl;                        \
        *reinterpret_cast<uint4*>(&Bh[b][bdst0]) = rBh0;                       \
        *reinterpret_cast<uint4*>(&Bh[b][bdst1]) = rBh1;                       \
        *reinterpret_cast<uint4*>(&Bl[b][bdst0]) = rBl0;                       \
        *reinterpret_cast<uint4*>(&Bl[b][bdst1]) = rBl1;                       \
    } while (0)

    f32x4 acc[4][4] = {};

    LOADT(0);
    WRITET(0);
    __syncthreads();

    const int nt = K >> 5;
    int cur = 0;
    for (int t = 0; t < nt; ++t) {
        if (t + 1 < nt) LOADT((t + 1) << 5);

        s16x8 bhf[4], blf[4];
        #pragma unroll
        for (int n = 0; n < 4; ++n) {
            int bc = wc * 64 + n * 16 + lr;
            int boff = bc * 32 + ((lq ^ (bc & 3)) * 8);
            bhf[n] = *reinterpret_cast<const s16x8*>(&Bh[cur][boff]);
            blf[n] = *reinterpret_cast<const s16x8*>(&Bl[cur][boff]);
        }
        #pragma unroll
        for (int m = 0; m < 4; ++m) {
            int ar = wr * 64 + m * 16 + lr;
            int aoff = ar * 32 + ((lq ^ (ar & 3)) * 8);
            s16x8 ah = *reinterpret_cast<const s16x8*>(&Ah[cur][aoff]);
            s16x8 al = *reinterpret_cast<const s16x8*>(&Al[cur][aoff]);
            #pragma unroll
            for (int n = 0; n < 4; ++n) {
                acc[m][n] = __builtin_amdgcn_mfma_f32_16x16x32_bf16(ah, bhf[n], acc[m][n], 0, 0, 0);
                acc[m][n] = __builtin_amdgcn_mfma_f32_16x16x32_bf16(ah, blf[n], acc[m][n], 0, 0, 0);
                acc[m][n] = __builtin_amdgcn_mfma_f32_16x16x32_bf16(al, bhf[n], acc[m][n], 0, 0, 0);
            }
        }

        if (t + 1 < nt) {
            WRITET(cur ^ 1);
            __syncthreads();
            cur ^= 1;
        }
    }
#undef LOADT
#undef WRITET

    // epilogue: frag layout col=lane&15, row=(lane>>4)*4+r (m89-verified)
    #pragma unroll
    for (int m = 0; m < 4; ++m) {
        #pragma unroll
        for (int n = 0; n < 4; ++n) {
            #pragma unroll
            for (int r = 0; r < 4; ++r) {
                int grow = brow + wr * 64 + m * 16 + lq * 4 + r;
                if (grow >= M) continue;
                int gcol = wc * 64 + n * 16 + lr;
                float v = acc[m][n][r] + bias[gcol];
                if (ACT == 1) v = fmaxf(v, 0.f);
                size_t o = (size_t)grow * ldc + gcol;
                if (OUTM == 0) {
                    Cf[o] = v;
                } else if (OUTM == 1) {
                    u16 h = f2bf(v);
                    Chi[o] = h;
                    Clo[o] = f2bf(v - bf2f(h));
                } else {
                    Chi[o] = f2h(v);
                }
            }
        }
    }
}

// ---------------------------------------------------------------------------
// fp32 tiled GEMM (final tiny layer, N=16): C = act(A@B + bias)
// ---------------------------------------------------------------------------
template<int BM, int BN, int BK, int TM, int TN, int ACT>
__global__ __launch_bounds__((BM / TM) * (BN / TN))
void gemm_k(const float* __restrict__ A, int lda,
            const float* __restrict__ B, int ldb,
            const float* __restrict__ bias,
            float* __restrict__ C, int ldc,
            int N, int K) {
    constexpr int THREADS = (BM / TM) * (BN / TN);
    __shared__ float As[BK][BM];
    __shared__ float Bs[BK][BN + 4];
    const int tid  = threadIdx.x;
    const int brow = blockIdx.y * BM;
    const int bcol = blockIdx.x * BN;
    constexpr int TCOLS = BN / TN;
    const int tcol = tid % TCOLS;
    const int trow = tid / TCOLS;
    float acc[TM][TN] = {};
    for (int k0 = 0; k0 < K; k0 += BK) {
        #pragma unroll
        for (int i = tid; i < BM * BK; i += THREADS) {
            int r = i / BK, c = i % BK;
            int gr = brow + r;
            As[c][r] = (gr < N) ? A[(size_t)gr * lda + (k0 + c)] : 0.f;
        }
        #pragma unroll
        for (int i = tid; i < BK * BN; i += THREADS) {
            int r = i / BN, c = i % BN;
            Bs[r][c] = B[(size_t)(k0 + r) * ldb + (bcol + c)];
        }
        __syncthreads();
        #pragma unroll
        for (int kk = 0; kk < BK; kk++) {
            float a[TM], b[TN];
            #pragma unroll
            for (int m = 0; m < TM; m++) a[m] = As[kk][trow * TM + m];
            #pragma unroll
            for (int n = 0; n < TN; n++) b[n] = Bs[kk][tcol * TN + n];
            #pragma unroll
            for (int m = 0; m < TM; m++)
                #pragma unroll
                for (int n = 0; n < TN; n++)
                    acc[m][n] = fmaf(a[m], b[n], acc[m][n]);
        }
        __syncthreads();
    }
    #pragma unroll
    for (int m = 0; m < TM; m++) {
        int gr = brow + trow * TM + m;
        if (gr >= N) continue;
        #pragma unroll
        for (int n = 0; n < TN; n++) {
            int gc = bcol + tcol * TN + n;
            float v = acc[m][n] + bias[gc];
            if (ACT == 1) v = fmaxf(v, 0.f);
            else if (ACT == 2) v = tanhf(v);
            C[(size_t)gr * ldc + gc] = v;
        }
    }
}

// ---------------------------------------------------------------------------
// Layer 1 (K=16) fused with hi/lo split epilogue
// ---------------------------------------------------------------------------
__global__ __launch_bounds__(256)
void pre1_k(const float* __restrict__ x, const float* __restrict__ w1,
            const float* __restrict__ b1,
            u16* __restrict__ t0hi, u16* __restrict__ t0lo, int M) {
    __shared__ float ws[16 * 256];
    __shared__ float xs[16][17];
    const int tid = threadIdx.x;
    for (int i = tid; i < 16 * 256; i += 256) ws[i] = w1[i];
    const int r0 = blockIdx.x * 16;
    {
        int rr = tid >> 4, cc = tid & 15;
        xs[rr][cc] = (r0 + rr < M) ? x[(size_t)(r0 + rr) * 16 + cc] : 0.f;
    }
    __syncthreads();
    const int c = tid;
    const float b = b1[c];
    for (int r = 0; r < 16; r++) {
        if (r0 + r >= M) break;
        float acc = b;
        #pragma unroll
        for (int k = 0; k < 16; k++) acc = fmaf(xs[r][k], ws[k * 256 + c], acc);
        acc = fmaxf(acc, 0.f);
        u16 h = f2bf(acc);
        t0hi[(size_t)(r0 + r) * 256 + c] = h;
        t0lo[(size_t)(r0 + r) * 256 + c] = f2bf(acc - bf2f(h));
    }
}

// weight split + transpose: W [K][N] fp32 -> hiT/loT [N][K] bf16
__global__ void wsplit_k(const float* __restrict__ W, u16* __restrict__ hiT,
                         u16* __restrict__ loT, int K, int N) {
    int i = blockIdx.x * blockDim.x + threadIdx.x;
    if (i >= K * N) return;
    int n = i / K, k = i % K;
    float v = W[(size_t)k * N + n];
    u16 h = f2bf(v);
    hiT[i] = h;
    loT[i] = f2bf(v - bf2f(h));
}

// ---------------------------------------------------------------------------
// CSR-by-destination build
// ---------------------------------------------------------------------------
__global__ void hist_k(const int* __restrict__ dst, int E, int* __restrict__ counts) {
    int i = blockIdx.x * blockDim.x + threadIdx.x;
    if (i < E) atomicAdd(&counts[dst[i]], 1);
}

__global__ void scan_k(const int* __restrict__ counts, int* __restrict__ offsets,
                       int* __restrict__ cursor, int n, int total) {
    __shared__ int sh[1024];
    const int t = threadIdx.x;
    const int chunk = (n + 1023) >> 10;
    const int lo = t * chunk;
    const int hi = min(lo + chunk, n);
    int s = 0;
    for (int i = lo; i < hi; i++) s += counts[i];
    sh[t] = s;
    __syncthreads();
    #pragma unroll
    for (int d = 1; d < 1024; d <<= 1) {
        int v = (t >= d) ? sh[t - d] : 0;
        __syncthreads();
        sh[t] += v;
        __syncthreads();
    }
    int off = sh[t] - s;
    for (int i = lo; i < hi; i++) {
        offsets[i] = off;
        cursor[i]  = off;
        off += counts[i];
    }
    if (t == 0) offsets[n] = total;
}

__global__ void fill_k(const int* __restrict__ src, const int* __restrict__ dst, int E,
                       int* __restrict__ cursor, int* __restrict__ sorted_src) {
    int i = blockIdx.x * blockDim.x + threadIdx.x;
    if (i < E) {
        int d = dst[i];
        int pos = atomicAdd(&cursor[d], 1);
        sorted_src[pos] = src[i];
    }
}

// ---------------------------------------------------------------------------
// Aggregate incoming messages from fp16 t rows (512 B each), fp32 accumulate,
// write hi/lo bf16 into hcat columns 256..511 (row stride 512).
// Unroll-4 over edges: 4 independent row loads in flight per wave.
// ---------------------------------------------------------------------------
__global__ void agg_k(const u16* __restrict__ t, const int* __restrict__ offsets,
                      const int* __restrict__ sorted_src,
                      u16* __restrict__ hi, u16* __restrict__ lo, int n) {
    const int node = blockIdx.x * (blockDim.x >> 6) + (threadIdx.x >> 6);
    const int lane = threadIdx.x & 63;
    if (node >= n) return;
    const int s0 = offsets[node], s1 = offsets[node + 1];

    float4 a0 = make_float4(0.f, 0.f, 0.f, 0.f);
    float4 a1 = a0, a2 = a0, a3 = a0;

    int i = s0;
    for (; i + 4 <= s1; i += 4) {
        int e0 = sorted_src[i];
        int e1 = sorted_src[i + 1];
        int e2 = sorted_src[i + 2];
        int e3 = sorted_src[i + 3];
        ushort4 v0 = *reinterpret_cast<const ushort4*>(t + (size_t)e0 * 256 + lane * 4);
        ushort4 v1 = *reinterpret_cast<const ushort4*>(t + (size_t)e1 * 256 + lane * 4);
        ushort4 v2 = *reinterpret_cast<const ushort4*>(t + (size_t)e2 * 256 + lane * 4);
        ushort4 v3 = *reinterpret_cast<const ushort4*>(t + (size_t)e3 * 256 + lane * 4);
        a0.x += h2f(v0.x); a0.y += h2f(v0.y); a0.z += h2f(v0.z); a0.w += h2f(v0.w);
        a1.x += h2f(v1.x); a1.y += h2f(v1.y); a1.z += h2f(v1.z); a1.w += h2f(v1.w);
        a2.x += h2f(v2.x); a2.y += h2f(v2.y); a2.z += h2f(v2.z); a2.w += h2f(v2.w);
        a3.x += h2f(v3.x); a3.y += h2f(v3.y); a3.z += h2f(v3.z); a3.w += h2f(v3.w);
    }
    for (; i < s1; ++i) {
        int e0 = sorted_src[i];
        ushort4 v0 = *reinterpret_cast<const ushort4*>(t + (size_t)e0 * 256 + lane * 4);
        a0.x += h2f(v0.x); a0.y += h2f(v0.y); a0.z += h2f(v0.z); a0.w += h2f(v0.w);
    }
    float4 acc;
    acc.x = (a0.x + a1.x) + (a2.x + a3.x);
    acc.y = (a0.y + a1.y) + (a2.y + a3.y);
    acc.z = (a0.z + a1.z) + (a2.z + a3.z);
    acc.w = (a0.w + a1.w) + (a2.w + a3.w);

    ushort4 h4, l4;
    h4.x = f2bf(acc.x); l4.x = f2bf(acc.x - bf2f(h4.x));
    h4.y = f2bf(acc.y); l4.y = f2bf(acc.y - bf2f(h4.y));
    h4.z = f2bf(acc.z); l4.z = f2bf(acc.z - bf2f(h4.z));
    h4.w = f2bf(acc.w); l4.w = f2bf(acc.w - bf2f(h4.w));
    size_t o = (size_t)node * 512 + 256 + (size_t)lane * 4;
    *reinterpret_cast<ushort4*>(hi + o) = h4;
    *reinterpret_cast<ushort4*>(lo + o) = l4;
}

// ---------------------------------------------------------------------------
extern "C" void kernel_launch(void* const* d_in, const int* in_sizes, int n_in,
                              void* d_out, int out_size, void* d_ws, size_t ws_size,
                              hipStream_t stream) {
    const float* x       = (const float*)d_in[0];
    const int*   edges   = (const int*)d_in[1];
    const float* pre_w1  = (const float*)d_in[2];
    const float* pre_b1  = (const float*)d_in[3];
    const float* pre_w2  = (const float*)d_in[4];
    const float* pre_b2  = (const float*)d_in[5];
    const float* conv_w  = (const float*)d_in[6];
    const float* conv_b  = (const float*)d_in[7];
    const float* post_w1 = (const float*)d_in[8];
    const float* post_b1 = (const float*)d_in[9];
    const float* post_w2 = (const float*)d_in[10];
    const float* post_b2 = (const float*)d_in[11];

    const int N = in_sizes[0] / 16;
    const int E = in_sizes[1] / 2;
    const int* src = edges;
    const int* dst = edges + E;

    // workspace layout
    u16*   hcat_hi = (u16*)d_ws;                           // N x 512
    u16*   hcat_lo = hcat_hi + (size_t)N * 512;            // N x 512
    float* Cbuf    = (float*)(hcat_lo + (size_t)N * 512);  // N x 256 f32 region
    u16*   tf16    = (u16*)Cbuf;                           // t as fp16 (dead before z)
    u16*   t0hi    = (u16*)Cbuf;                           // t0 dead before t written
    u16*   t0lo    = t0hi + (size_t)N * 256;
    u16*   w2hi    = (u16*)(Cbuf + (size_t)N * 256);
    u16*   w2lo    = w2hi + 256 * 256;
    u16*   cvhi    = w2lo + 256 * 256;
    u16*   cvlo    = cvhi + 256 * 256;
    u16*   p1hi    = cvlo + 256 * 256;
    u16*   p1lo    = p1hi + 512 * 256;
    int* offsets = (int*)(p1lo + 512 * 256);               // N+1
    int* counts  = offsets + (N + 1);                      // N
    int* cursor  = counts + N;                             // N
    int* sorted  = cursor + N;                             // E

    const dim3 blk(256);
    const dim3 g_mfma((N + 127) / 128);
    const dim3 blk_mfma(512);

    // weight splits (transposed)
    wsplit_k<<<(256 * 256 + 255) / 256, blk, 0, stream>>>(pre_w2, w2hi, w2lo, 256, 256);
    wsplit_k<<<(256 * 256 + 255) / 256, blk, 0, stream>>>(conv_w, cvhi, cvlo, 256, 256);
    wsplit_k<<<(512 * 256 + 255) / 256, blk, 0, stream>>>(post_w1, p1hi, p1lo, 512, 256);

    // CSR by destination (independent of GEMMs)
    hipMemsetAsync(counts, 0, (size_t)N * sizeof(int), stream);
    hist_k<<<(E + 255) / 256, blk, 0, stream>>>(dst, E, counts);
    scan_k<<<1, 1024, 0, stream>>>(counts, offsets, cursor, N, E);
    fill_k<<<(E + 255) / 256, blk, 0, stream>>>(src, dst, E, cursor, sorted);

    // 1. t0 = relu(x @ pre_w1 + b1), split hi/lo
    pre1_k<<<(N + 15) / 16, blk, 0, stream>>>(x, pre_w1, pre_b1, t0hi, t0lo, N);
    // 2. h = t0 @ pre_w2 + b2 -> hcat[:, :256] (hi/lo)
    mfma3_k<0, 1><<<g_mfma, blk_mfma, 0, stream>>>(t0hi, t0lo, 256, w2hi, w2lo, pre_b2,
                                                   nullptr, hcat_hi, hcat_lo, 512, N, 256);
    // 3. t = relu(h @ conv_w + cb) -> tf16 (fp16)
    mfma3_k<1, 2><<<g_mfma, blk_mfma, 0, stream>>>(hcat_hi, hcat_lo, 512, cvhi, cvlo, conv_b,
                                                   nullptr, tf16, nullptr, 256, N, 256);
    // 4. aggregate fp16 rows -> hcat[:, 256:] (hi/lo)
    agg_k<<<(N + 3) / 4, blk, 0, stream>>>(tf16, offsets, sorted, hcat_hi, hcat_lo, N);
    // 5. z = relu(hcat @ post_w1 + b1) -> Cbuf fp32 (t dead)
    mfma3_k<1, 0><<<g_mfma, blk_mfma, 0, stream>>>(hcat_hi, hcat_lo, 512, p1hi, p1lo, post_b1,
                                                   Cbuf, nullptr, nullptr, 256, N, 512);
    // 6. out = tanh(z @ post_w2 + b2), fp32 exact final layer
    gemm_k<64, 16, 16, 4, 1, 2><<<dim3(1, (N + 63) / 64), blk, 0, stream>>>(
        Cbuf, 256, post_w2, 16, post_b2, (float*)d_out, 16, N, 256);
}

// Round 5
// 387.837 us; speedup vs baseline: 2.4262x; 1.2774x over previous
//
#include <hip/hip_runtime.h>
#include <hip/hip_bf16.h>

using s16x8 = __attribute__((ext_vector_type(8))) short;   // 8 bf16 (4 VGPRs)
using f32x4 = __attribute__((ext_vector_type(4))) float;
using u16 = unsigned short;

__device__ __forceinline__ u16 f2bf(float v) {             // RNE fp32 -> bf16
    unsigned u = __float_as_uint(v);
    return (u16)((u + 0x7fffu + ((u >> 16) & 1u)) >> 16);
}
__device__ __forceinline__ float bf2f(u16 h) {
    return __uint_as_float(((unsigned)h) << 16);
}
__device__ __forceinline__ u16 f2h(float v) {              // fp32 -> fp16 RNE
    _Float16 h = (_Float16)v;
    u16 r; __builtin_memcpy(&r, &h, 2); return r;
}
__device__ __forceinline__ float h2f(u16 x) {
    _Float16 h; __builtin_memcpy(&h, &x, 2); return (float)h;
}

// ---------------------------------------------------------------------------
// bf16x3 MFMA GEMM, tile 128 rows x 256 cols (full width), K-step 32.
// 512 threads = 8 waves (2x4); each wave owns a 64x64 output tile.
// A hi/lo [M][K] row-major (lda); B hi/lo transposed [256][K] row-major.
// OUTM: 0 = fp32 Cf, 1 = bf16 hi/lo pair, 2 = fp16 (u16) into Chi.
// Reg-staged global loads for t+1 before compute of t; LDS dbuf; 1 barrier.
// ---------------------------------------------------------------------------
template<int ACT, int OUTM>
__global__ __launch_bounds__(512)
void mfma3_k(const u16* __restrict__ Ahi, const u16* __restrict__ Alo, int lda,
             const u16* __restrict__ BThi, const u16* __restrict__ BTlo,
             const float* __restrict__ bias,
             float* __restrict__ Cf, u16* __restrict__ Chi, u16* __restrict__ Clo,
             int ldc, int M, int K) {
    __shared__ u16 Ah[2][128 * 32];
    __shared__ u16 Al[2][128 * 32];
    __shared__ u16 Bh[2][256 * 32];
    __shared__ u16 Bl[2][256 * 32];   // total 96 KB

    const int tid  = threadIdx.x;
    const int brow = blockIdx.x * 128;
    const int lane = tid & 63;
    const int wid  = tid >> 6;
    const int wr = wid >> 2, wc = wid & 3;      // 2x4 wave grid
    const int lr = lane & 15, lq = lane >> 4;

    const int arow = tid >> 2;                  // 0..127
    const int ac   = tid & 3;                   // 8-elem chunk within 32-k
    const int adst = arow * 32 + ((ac ^ (arow & 3)) * 8);
    const int agrow = brow + arow;
    const bool aval = (agrow < M);
    const u16* pAh = Ahi + (size_t)agrow * lda + ac * 8;
    const u16* pAl = Alo + (size_t)agrow * lda + ac * 8;

    const int br0 = tid >> 2;
    const int br1 = 128 + br0;
    const int bdst0 = br0 * 32 + ((ac ^ (br0 & 3)) * 8);
    const int bdst1 = br1 * 32 + ((ac ^ (br1 & 3)) * 8);
    const u16* pBh0 = BThi + (size_t)br0 * K + ac * 8;
    const u16* pBh1 = BThi + (size_t)br1 * K + ac * 8;
    const u16* pBl0 = BTlo + (size_t)br0 * K + ac * 8;
    const u16* pBl1 = BTlo + (size_t)br1 * K + ac * 8;

    uint4 rAh, rAl, rBh0, rBh1, rBl0, rBl1;
    const uint4 z4 = make_uint4(0, 0, 0, 0);

#define LOADT(k0)                                                              \
    do {                                                                       \
        if (aval) {                                                            \
            rAh = *reinterpret_cast<const uint4*>(pAh + (k0));                 \
            rAl = *reinterpret_cast<const uint4*>(pAl + (k0));                 \
        } else { rAh = z4; rAl = z4; }                                         \
        rBh0 = *reinterpret_cast<const uint4*>(pBh0 + (k0));                   \
        rBh1 = *reinterpret_cast<const uint4*>(pBh1 + (k0));                   \
        rBl0 = *reinterpret_cast<const uint4*>(pBl0 + (k0));                   \
        rBl1 = *reinterpret_cast<const uint4*>(pBl1 + (k0));                   \
    } while (0)

#define WRITET(b)                                                              \
    do {                                                                       \
        *reinterpret_cast<uint4*>(&Ah[b][adst])  = rAh;                        \
        *reinterpret_cast<uint4*>(&Al[b][adst])  = rAl;                        \
        *reinterpret_cast<uint4*>(&Bh[b][bdst0]) = rBh0;                       \
        *reinterpret_cast<uint4*>(&Bh[b][bdst1]) = rBh1;                       \
        *reinterpret_cast<uint4*>(&Bl[b][bdst0]) = rBl0;                       \
        *reinterpret_cast<uint4*>(&Bl[b][bdst1]) = rBl1;                       \
    } while (0)

    f32x4 acc[4][4] = {};

    LOADT(0);
    WRITET(0);
    __syncthreads();

    const int nt = K >> 5;
    int cur = 0;
    for (int t = 0; t < nt; ++t) {
        if (t + 1 < nt) LOADT((t + 1) << 5);

        s16x8 bhf[4], blf[4];
        #pragma unroll
        for (int n = 0; n < 4; ++n) {
            int bc = wc * 64 + n * 16 + lr;
            int boff = bc * 32 + ((lq ^ (bc & 3)) * 8);
            bhf[n] = *reinterpret_cast<const s16x8*>(&Bh[cur][boff]);
            blf[n] = *reinterpret_cast<const s16x8*>(&Bl[cur][boff]);
        }
        #pragma unroll
        for (int m = 0; m < 4; ++m) {
            int ar = wr * 64 + m * 16 + lr;
            int aoff = ar * 32 + ((lq ^ (ar & 3)) * 8);
            s16x8 ah = *reinterpret_cast<const s16x8*>(&Ah[cur][aoff]);
            s16x8 al = *reinterpret_cast<const s16x8*>(&Al[cur][aoff]);
            #pragma unroll
            for (int n = 0; n < 4; ++n) {
                acc[m][n] = __builtin_amdgcn_mfma_f32_16x16x32_bf16(ah, bhf[n], acc[m][n], 0, 0, 0);
                acc[m][n] = __builtin_amdgcn_mfma_f32_16x16x32_bf16(ah, blf[n], acc[m][n], 0, 0, 0);
                acc[m][n] = __builtin_amdgcn_mfma_f32_16x16x32_bf16(al, bhf[n], acc[m][n], 0, 0, 0);
            }
        }

        if (t + 1 < nt) {
            WRITET(cur ^ 1);
            __syncthreads();
            cur ^= 1;
        }
    }
#undef LOADT
#undef WRITET

    // epilogue: frag layout col=lane&15, row=(lane>>4)*4+r (m89-verified)
    #pragma unroll
    for (int m = 0; m < 4; ++m) {
        #pragma unroll
        for (int n = 0; n < 4; ++n) {
            #pragma unroll
            for (int r = 0; r < 4; ++r) {
                int grow = brow + wr * 64 + m * 16 + lq * 4 + r;
                if (grow >= M) continue;
                int gcol = wc * 64 + n * 16 + lr;
                float v = acc[m][n][r] + bias[gcol];
                if (ACT == 1) v = fmaxf(v, 0.f);
                size_t o = (size_t)grow * ldc + gcol;
                if (OUTM == 0) {
                    Cf[o] = v;
                } else if (OUTM == 1) {
                    u16 h = f2bf(v);
                    Chi[o] = h;
                    Clo[o] = f2bf(v - bf2f(h));
                } else {
                    Chi[o] = f2h(v);
                }
            }
        }
    }
}

// ---------------------------------------------------------------------------
// fp32 tiled GEMM (final tiny layer, N=16): C = act(A@B + bias)
// ---------------------------------------------------------------------------
template<int BM, int BN, int BK, int TM, int TN, int ACT>
__global__ __launch_bounds__((BM / TM) * (BN / TN))
void gemm_k(const float* __restrict__ A, int lda,
            const float* __restrict__ B, int ldb,
            const float* __restrict__ bias,
            float* __restrict__ C, int ldc,
            int N, int K) {
    constexpr int THREADS = (BM / TM) * (BN / TN);
    __shared__ float As[BK][BM];
    __shared__ float Bs[BK][BN + 4];
    const int tid  = threadIdx.x;
    const int brow = blockIdx.y * BM;
    const int bcol = blockIdx.x * BN;
    constexpr int TCOLS = BN / TN;
    const int tcol = tid % TCOLS;
    const int trow = tid / TCOLS;
    float acc[TM][TN] = {};
    for (int k0 = 0; k0 < K; k0 += BK) {
        #pragma unroll
        for (int i = tid; i < BM * BK; i += THREADS) {
            int r = i / BK, c = i % BK;
            int gr = brow + r;
            As[c][r] = (gr < N) ? A[(size_t)gr * lda + (k0 + c)] : 0.f;
        }
        #pragma unroll
        for (int i = tid; i < BK * BN; i += THREADS) {
            int r = i / BN, c = i % BN;
            Bs[r][c] = B[(size_t)(k0 + r) * ldb + (bcol + c)];
        }
        __syncthreads();
        #pragma unroll
        for (int kk = 0; kk < BK; kk++) {
            float a[TM], b[TN];
            #pragma unroll
            for (int m = 0; m < TM; m++) a[m] = As[kk][trow * TM + m];
            #pragma unroll
            for (int n = 0; n < TN; n++) b[n] = Bs[kk][tcol * TN + n];
            #pragma unroll
            for (int m = 0; m < TM; m++)
                #pragma unroll
                for (int n = 0; n < TN; n++)
                    acc[m][n] = fmaf(a[m], b[n], acc[m][n]);
        }
        __syncthreads();
    }
    #pragma unroll
    for (int m = 0; m < TM; m++) {
        int gr = brow + trow * TM + m;
        if (gr >= N) continue;
        #pragma unroll
        for (int n = 0; n < TN; n++) {
            int gc = bcol + tcol * TN + n;
            float v = acc[m][n] + bias[gc];
            if (ACT == 1) v = fmaxf(v, 0.f);
            else if (ACT == 2) v = tanhf(v);
            C[(size_t)gr * ldc + gc] = v;
        }
    }
}

// ---------------------------------------------------------------------------
// Layer 1 (K=16) fused with hi/lo split epilogue
// ---------------------------------------------------------------------------
__global__ __launch_bounds__(256)
void pre1_k(const float* __restrict__ x, const float* __restrict__ w1,
            const float* __restrict__ b1,
            u16* __restrict__ t0hi, u16* __restrict__ t0lo, int M) {
    __shared__ float ws[16 * 256];
    __shared__ float xs[16][17];
    const int tid = threadIdx.x;
    for (int i = tid; i < 16 * 256; i += 256) ws[i] = w1[i];
    const int r0 = blockIdx.x * 16;
    {
        int rr = tid >> 4, cc = tid & 15;
        xs[rr][cc] = (r0 + rr < M) ? x[(size_t)(r0 + rr) * 16 + cc] : 0.f;
    }
    __syncthreads();
    const int c = tid;
    const float b = b1[c];
    for (int r = 0; r < 16; r++) {
        if (r0 + r >= M) break;
        float acc = b;
        #pragma unroll
        for (int k = 0; k < 16; k++) acc = fmaf(xs[r][k], ws[k * 256 + c], acc);
        acc = fmaxf(acc, 0.f);
        u16 h = f2bf(acc);
        t0hi[(size_t)(r0 + r) * 256 + c] = h;
        t0lo[(size_t)(r0 + r) * 256 + c] = f2bf(acc - bf2f(h));
    }
}

// weight split + transpose: W [K][N] fp32 -> hiT/loT [N][K] bf16
__global__ void wsplit_k(const float* __restrict__ W, u16* __restrict__ hiT,
                         u16* __restrict__ loT, int K, int N) {
    int i = blockIdx.x * blockDim.x + threadIdx.x;
    if (i >= K * N) return;
    int n = i / K, k = i % K;
    float v = W[(size_t)k * N + n];
    u16 h = f2bf(v);
    hiT[i] = h;
    loT[i] = f2bf(v - bf2f(h));
}

// ---------------------------------------------------------------------------
// CSR-by-destination build
// ---------------------------------------------------------------------------
__global__ void hist_k(const int* __restrict__ dst, int E, int* __restrict__ counts) {
    int i = blockIdx.x * blockDim.x + threadIdx.x;
    if (i < E) atomicAdd(&counts[dst[i]], 1);
}

// hierarchical scan, stage 1: per-block exclusive scan + block sums
__global__ __launch_bounds__(256)
void scan1_k(const int* __restrict__ counts, int* __restrict__ pre,
             int* __restrict__ bsum, int n) {
    __shared__ int sh[256];
    const int t = threadIdx.x;
    const int i = blockIdx.x * 256 + t;
    int v = (i < n) ? counts[i] : 0;
    sh[t] = v;
    __syncthreads();
    #pragma unroll
    for (int d = 1; d < 256; d <<= 1) {
        int x = (t >= d) ? sh[t - d] : 0;
        __syncthreads();
        sh[t] += x;
        __syncthreads();
    }
    if (i < n) pre[i] = sh[t] - v;                 // exclusive within block
    if (t == 255) bsum[blockIdx.x] = sh[255];      // block total
}

// stage 2: single block exclusive-scans the block sums (nb <= 256)
__global__ __launch_bounds__(256)
void scan2_k(int* __restrict__ bsum, int nb) {
    __shared__ int sh[256];
    const int t = threadIdx.x;
    int v = (t < nb) ? bsum[t] : 0;
    sh[t] = v;
    __syncthreads();
    #pragma unroll
    for (int d = 1; d < 256; d <<= 1) {
        int x = (t >= d) ? sh[t - d] : 0;
        __syncthreads();
        sh[t] += x;
        __syncthreads();
    }
    if (t < nb) bsum[t] = sh[t] - v;               // exclusive block offsets
}

// stage 3: add block offsets, emit offsets + cursor (+ sentinel)
__global__ __launch_bounds__(256)
void scan3_k(const int* __restrict__ pre, const int* __restrict__ bsum,
             int* __restrict__ offsets, int* __restrict__ cursor,
             int n, int total) {
    const int i = blockIdx.x * 256 + threadIdx.x;
    if (i < n) {
        int o = pre[i] + bsum[blockIdx.x];
        offsets[i] = o;
        cursor[i]  = o;
    }
    if (i == 0) offsets[n] = total;
}

__global__ void fill_k(const int* __restrict__ src, const int* __restrict__ dst, int E,
                       int* __restrict__ cursor, int* __restrict__ sorted_src) {
    int i = blockIdx.x * blockDim.x + threadIdx.x;
    if (i < E) {
        int d = dst[i];
        int pos = atomicAdd(&cursor[d], 1);
        sorted_src[pos] = src[i];
    }
}

// ---------------------------------------------------------------------------
// Aggregate incoming messages from fp16 t rows (512 B each), fp32 accumulate,
// write hi/lo bf16 into hcat columns 256..511 (row stride 512).
// Unroll-4 over edges: 4 independent row loads in flight per wave.
// ---------------------------------------------------------------------------
__global__ void agg_k(const u16* __restrict__ t, const int* __restrict__ offsets,
                      const int* __restrict__ sorted_src,
                      u16* __restrict__ hi, u16* __restrict__ lo, int n) {
    const int node = blockIdx.x * (blockDim.x >> 6) + (threadIdx.x >> 6);
    const int lane = threadIdx.x & 63;
    if (node >= n) return;
    const int s0 = offsets[node], s1 = offsets[node + 1];

    float4 a0 = make_float4(0.f, 0.f, 0.f, 0.f);
    float4 a1 = a0, a2 = a0, a3 = a0;

    int i = s0;
    for (; i + 4 <= s1; i += 4) {
        int e0 = sorted_src[i];
        int e1 = sorted_src[i + 1];
        int e2 = sorted_src[i + 2];
        int e3 = sorted_src[i + 3];
        ushort4 v0 = *reinterpret_cast<const ushort4*>(t + (size_t)e0 * 256 + lane * 4);
        ushort4 v1 = *reinterpret_cast<const ushort4*>(t + (size_t)e1 * 256 + lane * 4);
        ushort4 v2 = *reinterpret_cast<const ushort4*>(t + (size_t)e2 * 256 + lane * 4);
        ushort4 v3 = *reinterpret_cast<const ushort4*>(t + (size_t)e3 * 256 + lane * 4);
        a0.x += h2f(v0.x); a0.y += h2f(v0.y); a0.z += h2f(v0.z); a0.w += h2f(v0.w);
        a1.x += h2f(v1.x); a1.y += h2f(v1.y); a1.z += h2f(v1.z); a1.w += h2f(v1.w);
        a2.x += h2f(v2.x); a2.y += h2f(v2.y); a2.z += h2f(v2.z); a2.w += h2f(v2.w);
        a3.x += h2f(v3.x); a3.y += h2f(v3.y); a3.z += h2f(v3.z); a3.w += h2f(v3.w);
    }
    for (; i < s1; ++i) {
        int e0 = sorted_src[i];
        ushort4 v0 = *reinterpret_cast<const ushort4*>(t + (size_t)e0 * 256 + lane * 4);
        a0.x += h2f(v0.x); a0.y += h2f(v0.y); a0.z += h2f(v0.z); a0.w += h2f(v0.w);
    }
    float4 acc;
    acc.x = (a0.x + a1.x) + (a2.x + a3.x);
    acc.y = (a0.y + a1.y) + (a2.y + a3.y);
    acc.z = (a0.z + a1.z) + (a2.z + a3.z);
    acc.w = (a0.w + a1.w) + (a2.w + a3.w);

    ushort4 h4, l4;
    h4.x = f2bf(acc.x); l4.x = f2bf(acc.x - bf2f(h4.x));
    h4.y = f2bf(acc.y); l4.y = f2bf(acc.y - bf2f(h4.y));
    h4.z = f2bf(acc.z); l4.z = f2bf(acc.z - bf2f(h4.z));
    h4.w = f2bf(acc.w); l4.w = f2bf(acc.w - bf2f(h4.w));
    size_t o = (size_t)node * 512 + 256 + (size_t)lane * 4;
    *reinterpret_cast<ushort4*>(hi + o) = h4;
    *reinterpret_cast<ushort4*>(lo + o) = l4;
}

// ---------------------------------------------------------------------------
extern "C" void kernel_launch(void* const* d_in, const int* in_sizes, int n_in,
                              void* d_out, int out_size, void* d_ws, size_t ws_size,
                              hipStream_t stream) {
    const float* x       = (const float*)d_in[0];
    const int*   edges   = (const int*)d_in[1];
    const float* pre_w1  = (const float*)d_in[2];
    const float* pre_b1  = (const float*)d_in[3];
    const float* pre_w2  = (const float*)d_in[4];
    const float* pre_b2  = (const float*)d_in[5];
    const float* conv_w  = (const float*)d_in[6];
    const float* conv_b  = (const float*)d_in[7];
    const float* post_w1 = (const float*)d_in[8];
    const float* post_b1 = (const float*)d_in[9];
    const float* post_w2 = (const float*)d_in[10];
    const float* post_b2 = (const float*)d_in[11];

    const int N = in_sizes[0] / 16;
    const int E = in_sizes[1] / 2;
    const int* src = edges;
    const int* dst = edges + E;

    // workspace layout
    u16*   hcat_hi = (u16*)d_ws;                           // N x 512
    u16*   hcat_lo = hcat_hi + (size_t)N * 512;            // N x 512
    float* Cbuf    = (float*)(hcat_lo + (size_t)N * 512);  // N x 256 f32 region
    u16*   tf16    = (u16*)Cbuf;                           // t as fp16 (dead before z)
    u16*   t0hi    = (u16*)Cbuf;                           // t0 dead before t written
    u16*   t0lo    = t0hi + (size_t)N * 256;
    u16*   w2hi    = (u16*)(Cbuf + (size_t)N * 256);
    u16*   w2lo    = w2hi + 256 * 256;
    u16*   cvhi    = w2lo + 256 * 256;
    u16*   cvlo    = cvhi + 256 * 256;
    u16*   p1hi    = cvlo + 256 * 256;
    u16*   p1lo    = p1hi + 512 * 256;
    int* offsets = (int*)(p1lo + 512 * 256);               // N+1
    int* counts  = offsets + (N + 1);                      // N
    int* cursor  = counts + N;                             // N
    int* sorted  = cursor + N;                             // E
    int* pre     = sorted + E;                             // N (scan partials)
    int* bsum    = pre + N;                                // <=256 block sums

    const dim3 blk(256);
    const dim3 g_mfma((N + 127) / 128);
    const dim3 blk_mfma(512);
    const int nsb = (N + 255) / 256;                       // scan blocks (196)

    // weight splits (transposed)
    wsplit_k<<<(256 * 256 + 255) / 256, blk, 0, stream>>>(pre_w2, w2hi, w2lo, 256, 256);
    wsplit_k<<<(256 * 256 + 255) / 256, blk, 0, stream>>>(conv_w, cvhi, cvlo, 256, 256);
    wsplit_k<<<(512 * 256 + 255) / 256, blk, 0, stream>>>(post_w1, p1hi, p1lo, 512, 256);

    // CSR by destination (independent of GEMMs)
    hipMemsetAsync(counts, 0, (size_t)N * sizeof(int), stream);
    hist_k<<<(E + 255) / 256, blk, 0, stream>>>(dst, E, counts);
    scan1_k<<<nsb, blk, 0, stream>>>(counts, pre, bsum, N);
    scan2_k<<<1, blk, 0, stream>>>(bsum, nsb);
    scan3_k<<<nsb, blk, 0, stream>>>(pre, bsum, offsets, cursor, N, E);
    fill_k<<<(E + 255) / 256, blk, 0, stream>>>(src, dst, E, cursor, sorted);

    // 1. t0 = relu(x @ pre_w1 + b1), split hi/lo
    pre1_k<<<(N + 15) / 16, blk, 0, stream>>>(x, pre_w1, pre_b1, t0hi, t0lo, N);
    // 2. h = t0 @ pre_w2 + b2 -> hcat[:, :256] (hi/lo)
    mfma3_k<0, 1><<<g_mfma, blk_mfma, 0, stream>>>(t0hi, t0lo, 256, w2hi, w2lo, pre_b2,
                                                   nullptr, hcat_hi, hcat_lo, 512, N, 256);
    // 3. t = relu(h @ conv_w + cb) -> tf16 (fp16)
    mfma3_k<1, 2><<<g_mfma, blk_mfma, 0, stream>>>(hcat_hi, hcat_lo, 512, cvhi, cvlo, conv_b,
                                                   nullptr, tf16, nullptr, 256, N, 256);
    // 4. aggregate fp16 rows -> hcat[:, 256:] (hi/lo)
    agg_k<<<(N + 3) / 4, blk, 0, stream>>>(tf16, offsets, sorted, hcat_hi, hcat_lo, N);
    // 5. z = relu(hcat @ post_w1 + b1) -> Cbuf fp32 (t dead)
    mfma3_k<1, 0><<<g_mfma, blk_mfma, 0, stream>>>(hcat_hi, hcat_lo, 512, p1hi, p1lo, post_b1,
                                                   Cbuf, nullptr, nullptr, 256, N, 512);
    // 6. out = tanh(z @ post_w2 + b2), fp32 exact final layer
    gemm_k<64, 16, 16, 4, 1, 2><<<dim3(1, (N + 63) / 64), blk, 0, stream>>>(
        Cbuf, 256, post_w2, 16, post_b2, (float*)d_out, 16, N, 256);
}